// Round 5
// baseline (201.503 us; speedup 1.0000x reference)
//
#include <hip/hip_runtime.h>
#include <hip/hip_bf16.h>
#include <stdint.h>

#define BATCH 8
#define SEQN  4096
#define DIM   128

typedef __attribute__((ext_vector_type(16))) float f32x16;
typedef __bf16 bf16x8 __attribute__((ext_vector_type(8)));

#define GAS __attribute__((address_space(1)))
#define LAS __attribute__((address_space(3)))

__device__ __forceinline__ ushort f2b(float x) {
  union { float f; uint32_t u; } a; a.f = x;
  uint32_t r = a.u + 0x7fffu + ((a.u >> 16) & 1u);   // RNE
  return (ushort)(r >> 16);
}
__device__ __forceinline__ uint32_t pkbf(float a, float b) {
  union { __bf16 h[2]; uint32_t u; } x;
  x.h[0] = (__bf16)a; x.h[1] = (__bf16)b;
  return x.u;
}

// Fragment-major layouts, per 32-row chunk g (global row/32), 4096 elems/chunk:
//   Q/K: slot = (kc*2+hi)*32 + ql holds  X[g*32+ql][16*kc+8*hi + 0..7]
//   V^T: slot = (db*4+ks*2+hi)*32 + ql holds V[g*32 + 16*ks+8*hi + 0..7][32*db+ql]

__global__ __launch_bounds__(256) void prep_qk(
    const float* __restrict__ qk, ushort* __restrict__ qfb, ushort* __restrict__ kfb) {
  __shared__ ushort qt_l[32 * 136];
  __shared__ ushort kt_l[32 * 136];
  const int g = blockIdx.x;
  const int t = threadIdx.x;
  const int r = t >> 3, s = t & 7;
  const float* src = qk + (size_t)g * 4096 + r * 128 + s * 16;
  float x[16];
  #pragma unroll
  for (int i = 0; i < 4; ++i) {
    float4 f = ((const float4*)src)[i];
    x[4*i] = f.x; x[4*i+1] = f.y; x[4*i+2] = f.z; x[4*i+3] = f.w;
  }
  float ss = 0.f;
  #pragma unroll
  for (int i = 0; i < 16; ++i) ss += x[i] * x[i];
  ss += __shfl_xor(ss, 1, 64);
  ss += __shfl_xor(ss, 2, 64);
  ss += __shfl_xor(ss, 4, 64);
  float rn = 1.0f / fmaxf(sqrtf(ss), 1e-12f);
  const float SC = 1.44269504088896340736f / 11.313708498984761f; // log2e/sqrt(128)
  float rs = rn * SC;
  #pragma unroll
  for (int j = 0; j < 16; ++j) {
    qt_l[r * 136 + s * 16 + j] = f2b(x[j]);
    kt_l[r * 136 + s * 16 + j] = f2b(x[j] * rs);
  }
  __syncthreads();
  #pragma unroll
  for (int p = 0; p < 2; ++p) {
    int sl = t + 256 * p;
    int qli = sl & 31, grp = sl >> 5;
    union { ushort u[8]; int4 v; } tq, tk;
    #pragma unroll
    for (int j = 0; j < 8; ++j) {
      tq.u[j] = qt_l[qli * 136 + grp * 8 + j];
      tk.u[j] = kt_l[qli * 136 + grp * 8 + j];
    }
    *(int4*)(qfb + (size_t)g * 4096 + sl * 8) = tq.v;
    *(int4*)(kfb + (size_t)g * 4096 + sl * 8) = tk.v;
  }
}

__global__ __launch_bounds__(256) void prep_v(
    const float* __restrict__ v, ushort* __restrict__ vfb) {
  __shared__ ushort vt_l[32 * 136];
  const int g = blockIdx.x;
  const int t = threadIdx.x;
  const int r = t >> 3, s = t & 7;
  const float* src = v + (size_t)g * 4096 + r * 128 + s * 16;
  #pragma unroll
  for (int i = 0; i < 4; ++i) {
    float4 f = ((const float4*)src)[i];
    vt_l[r * 136 + s * 16 + 4*i]     = f2b(f.x);
    vt_l[r * 136 + s * 16 + 4*i + 1] = f2b(f.y);
    vt_l[r * 136 + s * 16 + 4*i + 2] = f2b(f.z);
    vt_l[r * 136 + s * 16 + 4*i + 3] = f2b(f.w);
  }
  __syncthreads();
  #pragma unroll
  for (int p = 0; p < 2; ++p) {
    int sl = t + 256 * p;
    int qli = sl & 31, grp = sl >> 5;
    int db = grp >> 2, ks = (grp >> 1) & 1, hh = grp & 1;
    union { ushort u[8]; int4 v; } tv;
    #pragma unroll
    for (int j = 0; j < 8; ++j)
      tv.u[j] = vt_l[(16 * ks + 8 * hh + j) * 136 + 32 * db + qli];
    *(int4*)(vfb + (size_t)g * 4096 + sl * 8) = tv.v;
  }
}

// 8 waves = 2 qc x 4 hf; K direct from L2; Q in regs; V dbuf LDS; static-max softmax.
__global__ __launch_bounds__(512, 4) void attn_kernel(
    const ushort* __restrict__ qfb, const ushort* __restrict__ kfb,
    const ushort* __restrict__ vfb, float* __restrict__ out) {
  __shared__ ushort lds[40960];  // 80KB: V dbuf [0,65536)B; combine reuses all

  const int tid = threadIdx.x;
  const int w  = tid >> 6;
  const int l  = tid & 63;
  const int ql = l & 31;
  const int hi = l >> 5;
  const int qc = w & 1;
  const int hf = w >> 1;

  const int bidx  = blockIdx.x;
  const int batch = bidx & 7;             // XCD b holds batch b's K/V in its L2
  const int qt    = bidx >> 3;            // 0..63
  const int q0    = qt * 64 + qc * 32;
  const size_t kvch0 = (size_t)batch * 128 + hf * 32;

  // ---- Q fragments once, straight from global (fragment-major, coalesced) ----
  bf16x8 qf[8];
  {
    const ushort* qp = qfb + ((size_t)batch * 128 + qt * 2 + qc) * 4096 + l * 8;
    #pragma unroll
    for (int kc = 0; kc < 8; ++kc) qf[kc] = *(const bf16x8*)(qp + kc * 512);
  }

#define STAGE(bsel, t_) do {                                                   \
    const ushort* vsrc_ = vfb + (kvch0 + (t_)) * 4096 + qc * 2048 + l * 8;     \
    _Pragma("unroll")                                                          \
    for (int i_ = 0; i_ < 4; ++i_)                                             \
      __builtin_amdgcn_global_load_lds((const GAS uint32_t*)(vsrc_ + i_ * 512),\
          (LAS uint32_t*)(lds + ((bsel) * 32768 + hf * 8192 + qc * 4096 +      \
                                 i_ * 1024) / 2), 16, 0, 0);                   \
  } while (0)

  STAGE(0, 0);
  asm volatile("s_waitcnt vmcnt(0)" ::: "memory");
  __syncthreads();

  f32x16 o[4];
  #pragma unroll
  for (int db = 0; db < 4; ++db)
    #pragma unroll
    for (int r = 0; r < 16; ++r) o[db][r] = 0.f;
  float lsum = 0.f;

  int buf = 0;
  for (int t = 0; t < 32; ++t) {
    if (t + 1 < 32) STAGE(buf ^ 1, t + 1);

    // ---- K fragments from global (L2-resident, coalesced) ----
    const ushort* kt_p = kfb + (kvch0 + t) * 4096 + l * 8;
    bf16x8 kf[8];
    #pragma unroll
    for (int kc = 0; kc < 8; ++kc) kf[kc] = *(const bf16x8*)(kt_p + kc * 512);

    // ---- S^T = K * Q^T ----
    f32x16 st;
    #pragma unroll
    for (int r = 0; r < 16; ++r) st[r] = 0.f;
    __builtin_amdgcn_s_setprio(1);
    #pragma unroll
    for (int kc = 0; kc < 8; ++kc)
      st = __builtin_amdgcn_mfma_f32_32x32x16_bf16(kf[kc], qf[kc], st, 0, 0, 0);
    __builtin_amdgcn_s_setprio(0);

    // ---- diagonal mask ----
    const int kv0g = hf * 1024 + t * 32;
    if (kv0g == q0) {
      #pragma unroll
      for (int r = 0; r < 16; ++r) {
        int crow = (r & 3) + 8 * (r >> 2) + 4 * hi;
        if (crow == ql) st[r] = -1e30f;
      }
    }

    // ---- static-max softmax: P = exp2(s) raw (|s| <~ 0.8, no overflow) ----
    float p[16];
    float rs_ = 0.f;
    #pragma unroll
    for (int r = 0; r < 16; ++r) {
      p[r] = exp2f(st[r]);
      rs_ += p[r];
    }
    lsum += rs_;            // half-partial; cross-half summed in combine

    // ---- pack to bf16 words; half-exchange via v_permlane32_swap_b32 ----
    uint32_t ww[4][2];
    #pragma unroll
    for (int g4 = 0; g4 < 4; ++g4) {
      ww[g4][0] = pkbf(p[4 * g4 + 0], p[4 * g4 + 1]);
      ww[g4][1] = pkbf(p[4 * g4 + 2], p[4 * g4 + 3]);
    }
    bf16x8 pa[2];
    #pragma unroll
    for (int ks = 0; ks < 2; ++ks) {
      uint32_t a0 = ww[2 * ks][0], b0 = ww[2 * ks + 1][0];
      uint32_t a1 = ww[2 * ks][1], b1 = ww[2 * ks + 1][1];
      asm volatile("v_permlane32_swap_b32 %0, %1" : "+v"(a0), "+v"(b0));
      asm volatile("v_permlane32_swap_b32 %0, %1" : "+v"(a1), "+v"(b1));
      union { uint32_t u[4]; bf16x8 v; } pb;
      pb.u[0] = a0; pb.u[1] = a1; pb.u[2] = b0; pb.u[3] = b1;
      pa[ks] = pb.v;
    }

    // ---- O^T += V^T * P^T ----
    const ushort* vlp = lds + (buf * 16384 + hf * 4096) + l * 8;
    __builtin_amdgcn_s_setprio(1);
    #pragma unroll
    for (int db = 0; db < 4; ++db)
      #pragma unroll
      for (int ks = 0; ks < 2; ++ks) {
        bf16x8 vv = *(const bf16x8*)(vlp + (db * 4 + ks * 2) * 256);
        o[db] = __builtin_amdgcn_mfma_f32_32x32x16_bf16(vv, pa[ks], o[db], 0, 0, 0);
      }
    __builtin_amdgcn_s_setprio(0);

    asm volatile("s_waitcnt vmcnt(0)" ::: "memory");
    __syncthreads();
    buf ^= 1;
  }
#undef STAGE

  // ---- combine: sum l partials, tree-sum O across hf, normalize, store ----
  float* flds = (float*)lds;
  flds[(4 * hf + 2 * qc + hi) * 32 + ql] = lsum;
  __syncthreads();
  float L = 0.f;
  #pragma unroll
  for (int i = 0; i < 4; ++i) {
    L += flds[(4 * i + 2 * qc + 0) * 32 + ql];
    L += flds[(4 * i + 2 * qc + 1) * 32 + ql];
  }
  float* oA = flds + 512 + qc * 8704;   // [128][34]
  float* oB = oA + 4352;

  if (hf == 3 || hf == 1) {
    float* dst = (hf == 3) ? oA : oB;
    #pragma unroll
    for (int db = 0; db < 4; ++db)
      #pragma unroll
      for (int r = 0; r < 16; ++r) {
        int crow = (r & 3) + 8 * (r >> 2) + 4 * hi;
        dst[(32 * db + crow) * 34 + ql] = o[db][r];
      }
  }
  __syncthreads();
  if (hf == 2 || hf == 0) {
    float* dst = (hf == 2) ? oA : oB;
    #pragma unroll
    for (int db = 0; db < 4; ++db)
      #pragma unroll
      for (int r = 0; r < 16; ++r) {
        int crow = (r & 3) + 8 * (r >> 2) + 4 * hi;
        dst[(32 * db + crow) * 34 + ql] += o[db][r];
      }
  }
  __syncthreads();
  if (hf == 0) {
    const float inv = 1.0f / L;
    float* epw = flds + 17920 + qc * 1088;
    float* outb = out + (size_t)batch * SEQN * DIM;
    #pragma unroll
    for (int db = 0; db < 4; ++db) {
      float fin[16];
      #pragma unroll
      for (int r = 0; r < 16; ++r) {
        int crow = (r & 3) + 8 * (r >> 2) + 4 * hi;
        int idx = (32 * db + crow) * 34 + ql;
        fin[r] = (oA[idx] + oB[idx]) * inv;
      }
      #pragma unroll
      for (int rr = 0; rr < 8; ++rr) {
        int r0 = 2 * rr;
        int crow = (r0 & 3) + 8 * (r0 >> 2) + 4 * hi;
        *(float2*)(epw + ql * 34 + crow) = make_float2(fin[r0], fin[r0 + 1]);
      }
      __builtin_amdgcn_s_waitcnt(0);
      #pragma unroll
      for (int s2 = 0; s2 < 8; ++s2) {
        int row = 4 * s2 + (l >> 4);
        int c2  = l & 15;
        float2 v2 = *(const float2*)(epw + row * 34 + 2 * c2);
        *(float2*)(outb + (size_t)(q0 - qc * 32 + qc * 32 + row) * DIM + 32 * db + 2 * c2) = v2;
      }
      __builtin_amdgcn_s_waitcnt(0);
    }
  }
}

extern "C" void kernel_launch(void* const* d_in, const int* in_sizes, int n_in,
                              void* d_out, int out_size, void* d_ws, size_t ws_size,
                              hipStream_t stream) {
  (void)in_sizes; (void)n_in; (void)out_size; (void)ws_size;
  const float* qk = (const float*)d_in[0];
  const float* v  = (const float*)d_in[1];
  float* out = (float*)d_out;
  size_t nelem = (size_t)BATCH * SEQN * DIM;
  ushort* qfb = (ushort*)d_ws;
  ushort* kfb = qfb + nelem;
  ushort* vfb = kfb + nelem;
  prep_qk<<<BATCH * SEQN / 32, 256, 0, stream>>>(qk, qfb, kfb);
  prep_v <<<BATCH * SEQN / 32, 256, 0, stream>>>(v, vfb);
  attn_kernel<<<BATCH * (SEQN / 64), 512, 0, stream>>>(qfb, kfb, vfb, out);
}

// Round 6
// 115.090 us; speedup vs baseline: 1.7508x; 1.7508x over previous
//
#include <hip/hip_runtime.h>
#include <hip/hip_bf16.h>
#include <stdint.h>

#define BATCH 8
#define SEQN  4096
#define DIM   128
#define NT    32              // 32-kv tiles per quarter (1024 kv)

typedef __attribute__((ext_vector_type(16))) float f32x16;
typedef __bf16 bf16x8 __attribute__((ext_vector_type(8)));

#define GAS __attribute__((address_space(1)))
#define LAS __attribute__((address_space(3)))

__device__ __forceinline__ ushort f2b(float x) {
  union { float f; uint32_t u; } a; a.f = x;
  uint32_t r = a.u + 0x7fffu + ((a.u >> 16) & 1u);   // RNE
  return (ushort)(r >> 16);
}
__device__ __forceinline__ uint32_t pkbf(float a, float b) {
  union { __bf16 h[2]; uint32_t u; } x;
  x.h[0] = (__bf16)a; x.h[1] = (__bf16)b;
  return x.u;
}

// Fragment-major layouts, per 32-row chunk g (global row/32), 4096 elems/chunk:
//   Q/K: slot = (kc*2+hi)*32 + ql holds  X[g*32+ql][16*kc+8*hi + 0..7]
//   V^T: slot = (db*4+ks*2+hi)*32 + ql holds V[g*32 + 16*ks+8*hi + 0..7][32*db+ql]

__global__ __launch_bounds__(256) void prep_qk(
    const float* __restrict__ qk, ushort* __restrict__ qfb, ushort* __restrict__ kfb) {
  __shared__ ushort qt_l[32 * 136];
  __shared__ ushort kt_l[32 * 136];
  const int g = blockIdx.x;
  const int t = threadIdx.x;
  const int r = t >> 3, s = t & 7;
  const float* src = qk + (size_t)g * 4096 + r * 128 + s * 16;
  float x[16];
  #pragma unroll
  for (int i = 0; i < 4; ++i) {
    float4 f = ((const float4*)src)[i];
    x[4*i] = f.x; x[4*i+1] = f.y; x[4*i+2] = f.z; x[4*i+3] = f.w;
  }
  float ss = 0.f;
  #pragma unroll
  for (int i = 0; i < 16; ++i) ss += x[i] * x[i];
  ss += __shfl_xor(ss, 1, 64);
  ss += __shfl_xor(ss, 2, 64);
  ss += __shfl_xor(ss, 4, 64);
  float rn = 1.0f / fmaxf(sqrtf(ss), 1e-12f);
  const float SC = 1.44269504088896340736f / 11.313708498984761f; // log2e/sqrt(128)
  float rs = rn * SC;
  #pragma unroll
  for (int j = 0; j < 16; ++j) {
    qt_l[r * 136 + s * 16 + j] = f2b(x[j]);
    kt_l[r * 136 + s * 16 + j] = f2b(x[j] * rs);
  }
  __syncthreads();
  #pragma unroll
  for (int p = 0; p < 2; ++p) {
    int sl = t + 256 * p;
    int qli = sl & 31, grp = sl >> 5;
    union { ushort u[8]; int4 v; } tq, tk;
    #pragma unroll
    for (int j = 0; j < 8; ++j) {
      tq.u[j] = qt_l[qli * 136 + grp * 8 + j];
      tk.u[j] = kt_l[qli * 136 + grp * 8 + j];
    }
    *(int4*)(qfb + (size_t)g * 4096 + sl * 8) = tq.v;
    *(int4*)(kfb + (size_t)g * 4096 + sl * 8) = tk.v;
  }
}

__global__ __launch_bounds__(256) void prep_v(
    const float* __restrict__ v, ushort* __restrict__ vfb) {
  __shared__ ushort vt_l[32 * 136];
  const int g = blockIdx.x;
  const int t = threadIdx.x;
  const int r = t >> 3, s = t & 7;
  const float* src = v + (size_t)g * 4096 + r * 128 + s * 16;
  #pragma unroll
  for (int i = 0; i < 4; ++i) {
    float4 f = ((const float4*)src)[i];
    vt_l[r * 136 + s * 16 + 4*i]     = f2b(f.x);
    vt_l[r * 136 + s * 16 + 4*i + 1] = f2b(f.y);
    vt_l[r * 136 + s * 16 + 4*i + 2] = f2b(f.z);
    vt_l[r * 136 + s * 16 + 4*i + 3] = f2b(f.w);
  }
  __syncthreads();
  #pragma unroll
  for (int p = 0; p < 2; ++p) {
    int sl = t + 256 * p;
    int qli = sl & 31, grp = sl >> 5;
    int db = grp >> 2, ks = (grp >> 1) & 1, hh = grp & 1;
    union { ushort u[8]; int4 v; } tv;
    #pragma unroll
    for (int j = 0; j < 8; ++j)
      tv.u[j] = vt_l[(16 * ks + 8 * hh + j) * 136 + 32 * db + qli];
    *(int4*)(vfb + (size_t)g * 4096 + sl * 8) = tv.v;
  }
}

// 4 waves/block; wave w owns 64 q rows x KV quarter w; barrier-free main loop.
__global__ __launch_bounds__(256, 2) void attn_kernel(
    const ushort* __restrict__ qfb, const ushort* __restrict__ kfb,
    const ushort* __restrict__ vfb, float* __restrict__ out) {
  __shared__ ushort lds[40960];  // 80KB: V [0,64KB) 4x(2x8KB dbuf), Q [64,80KB)

  const int tid = threadIdx.x;
  const int w  = tid >> 6;       // KV quarter
  const int l  = tid & 63;
  const int ql = l & 31;
  const int hi = l >> 5;

  const int bidx  = blockIdx.x;
  const int batch = bidx & 7;             // XCD b gets batch b (K+V L2-resident)
  const int qt    = bidx >> 3;            // 0..63
  const int q0    = qt * 64;
  const size_t cb = (size_t)batch * 128;  // 32-row chunk index base

  const ushort* kq = kfb + (cb + w * 32) * 4096;  // K quarter (chunk stride 4096)
  const ushort* vq = vfb + (cb + w * 32) * 4096;
  ushort* myv = lds + w * 8192;           // 16KB private V dbuf (ushort units)
  ushort* ldsq = lds + 32768;             // Q [2 chunks][4096]

  // ---- prologue: stage Q (16KB block-wide), V tile 0, K tile 0 ----
  {
    const ushort* qsrc = qfb + (cb + qt * 2) * 4096 + tid * 8;
    #pragma unroll
    for (int i = 0; i < 4; ++i)
      __builtin_amdgcn_global_load_lds((const GAS uint32_t*)(qsrc + i * 2048),
          (LAS uint32_t*)(ldsq + i * 2048 + tid * 8), 16, 0, 0);
  }

#define STAGE(bsel, t_) do {                                                   \
    const ushort* vsrc_ = vq + (size_t)(t_) * 4096 + l * 8;                    \
    ushort* vdst_ = myv + (bsel) * 4096 + l * 8;                               \
    _Pragma("unroll")                                                          \
    for (int i_ = 0; i_ < 8; ++i_)                                             \
      __builtin_amdgcn_global_load_lds((const GAS uint32_t*)(vsrc_ + i_ * 512),\
          (LAS uint32_t*)(vdst_ + i_ * 512), 16, 0, 0);                        \
  } while (0)

  STAGE(0, 0);
  bf16x8 kf[8];
  {
    const ushort* kt_p = kq + l * 8;
    #pragma unroll
    for (int kc = 0; kc < 8; ++kc) kf[kc] = *(const bf16x8*)(kt_p + kc * 512);
  }
  __syncthreads();   // Q visible to all waves (drains prologue loads too)

  f32x16 o[8];       // [chunk c][db]: o[c*4+db]
  #pragma unroll
  for (int i = 0; i < 8; ++i)
    #pragma unroll
    for (int r = 0; r < 16; ++r) o[i][r] = 0.f;
  float lsum0 = 0.f, lsum1 = 0.f;

  int buf = 0;
  for (int t = 0; t < NT; ++t) {
    if (t + 1 < NT) STAGE(buf ^ 1, t + 1);

    bf16x8 pa[2][2];
    // ---- chunk 0: QK -> softmax -> pack ----
    {
      f32x16 st;
      #pragma unroll
      for (int r = 0; r < 16; ++r) st[r] = 0.f;
      const ushort* qlp = ldsq + l * 8;
      __builtin_amdgcn_s_setprio(1);
      #pragma unroll
      for (int kc = 0; kc < 8; ++kc) {
        bf16x8 qf = *(const bf16x8*)(qlp + kc * 512);
        st = __builtin_amdgcn_mfma_f32_32x32x16_bf16(kf[kc], qf, st, 0, 0, 0);
      }
      __builtin_amdgcn_s_setprio(0);
      if (w * 1024 + t * 32 == q0) {
        #pragma unroll
        for (int r = 0; r < 16; ++r) {
          int crow = (r & 3) + 8 * (r >> 2) + 4 * hi;
          if (crow == ql) st[r] = -1e30f;
        }
      }
      float p[16]; float rs_ = 0.f;
      #pragma unroll
      for (int r = 0; r < 16; ++r) { p[r] = exp2f(st[r]); rs_ += p[r]; }
      lsum0 += rs_;
      uint32_t ww[4][2];
      #pragma unroll
      for (int g4 = 0; g4 < 4; ++g4) {
        ww[g4][0] = pkbf(p[4 * g4 + 0], p[4 * g4 + 1]);
        ww[g4][1] = pkbf(p[4 * g4 + 2], p[4 * g4 + 3]);
      }
      #pragma unroll
      for (int ks = 0; ks < 2; ++ks) {
        uint32_t a0 = ww[2 * ks][0], b0 = ww[2 * ks + 1][0];
        uint32_t a1 = ww[2 * ks][1], b1 = ww[2 * ks + 1][1];
        asm volatile("v_permlane32_swap_b32 %0, %1" : "+v"(a0), "+v"(b0));
        asm volatile("v_permlane32_swap_b32 %0, %1" : "+v"(a1), "+v"(b1));
        union { uint32_t u[4]; bf16x8 v; } pb;
        pb.u[0] = a0; pb.u[1] = a1; pb.u[2] = b0; pb.u[3] = b1;
        pa[0][ks] = pb.v;
      }
    }
    // ---- chunk 1: QK -> softmax -> pack ----
    {
      f32x16 st;
      #pragma unroll
      for (int r = 0; r < 16; ++r) st[r] = 0.f;
      const ushort* qlp = ldsq + 4096 + l * 8;
      __builtin_amdgcn_s_setprio(1);
      #pragma unroll
      for (int kc = 0; kc < 8; ++kc) {
        bf16x8 qf = *(const bf16x8*)(qlp + kc * 512);
        st = __builtin_amdgcn_mfma_f32_32x32x16_bf16(kf[kc], qf, st, 0, 0, 0);
      }
      __builtin_amdgcn_s_setprio(0);
      // ---- prefetch K(t+1): kf dead after chunk-1 QK ----
      if (t + 1 < NT) {
        const ushort* kt_p = kq + (size_t)(t + 1) * 4096 + l * 8;
        #pragma unroll
        for (int kc = 0; kc < 8; ++kc) kf[kc] = *(const bf16x8*)(kt_p + kc * 512);
      }
      if (w * 1024 + t * 32 == q0 + 32) {
        #pragma unroll
        for (int r = 0; r < 16; ++r) {
          int crow = (r & 3) + 8 * (r >> 2) + 4 * hi;
          if (crow == ql) st[r] = -1e30f;
        }
      }
      float p[16]; float rs_ = 0.f;
      #pragma unroll
      for (int r = 0; r < 16; ++r) { p[r] = exp2f(st[r]); rs_ += p[r]; }
      lsum1 += rs_;
      uint32_t ww[4][2];
      #pragma unroll
      for (int g4 = 0; g4 < 4; ++g4) {
        ww[g4][0] = pkbf(p[4 * g4 + 0], p[4 * g4 + 1]);
        ww[g4][1] = pkbf(p[4 * g4 + 2], p[4 * g4 + 3]);
      }
      #pragma unroll
      for (int ks = 0; ks < 2; ++ks) {
        uint32_t a0 = ww[2 * ks][0], b0 = ww[2 * ks + 1][0];
        uint32_t a1 = ww[2 * ks][1], b1 = ww[2 * ks + 1][1];
        asm volatile("v_permlane32_swap_b32 %0, %1" : "+v"(a0), "+v"(b0));
        asm volatile("v_permlane32_swap_b32 %0, %1" : "+v"(a1), "+v"(b1));
        union { uint32_t u[4]; bf16x8 v; } pb;
        pb.u[0] = a0; pb.u[1] = a1; pb.u[2] = b0; pb.u[3] = b1;
        pa[1][ks] = pb.v;
      }
    }

    // ---- ensure this tile's V staging landed (in-order vmcnt; see theory) ----
    asm volatile("s_waitcnt vmcnt(16)" ::: "memory");
    __builtin_amdgcn_sched_barrier(0);

    // ---- O^T += V^T * P^T : V read once, feeds both chunks ----
    const ushort* vlp = myv + buf * 4096 + l * 8;
    __builtin_amdgcn_s_setprio(1);
    #pragma unroll
    for (int db = 0; db < 4; ++db)
      #pragma unroll
      for (int ks = 0; ks < 2; ++ks) {
        bf16x8 vv = *(const bf16x8*)(vlp + (db * 4 + ks * 2) * 256);
        o[db]     = __builtin_amdgcn_mfma_f32_32x32x16_bf16(vv, pa[0][ks], o[db],     0, 0, 0);
        o[4 + db] = __builtin_amdgcn_mfma_f32_32x32x16_bf16(vv, pa[1][ks], o[4 + db], 0, 0, 0);
      }
    __builtin_amdgcn_s_setprio(0);
    buf ^= 1;
  }
#undef STAGE

  // ---- epilogue: combine 4 quarters via LDS tree, normalize, store ----
  __syncthreads();
  float* A  = (float*)lds;          // [64 q][132] f32
  float* Bb = A + 8448;             // [64 q][132]
  float* lt = A + 16896;            // [4 w][2 hi][2 c][32 ql]
  float* Lf = A + 17408;            // inv-l per q row [64]

  lt[((w * 2 + hi) * 2 + 0) * 32 + ql] = lsum0;
  lt[((w * 2 + hi) * 2 + 1) * 32 + ql] = lsum1;
  __syncthreads();
  float L0 = 0.f, L1 = 0.f;
  #pragma unroll
  for (int i = 0; i < 8; ++i) {
    L0 += lt[(i * 2 + 0) * 32 + ql];
    L1 += lt[(i * 2 + 1) * 32 + ql];
  }
  if (w == 0 && hi == 0) { Lf[ql] = 1.0f / L0; Lf[32 + ql] = 1.0f / L1; }

  if (w == 3 || w == 1) {
    float* D = (w == 3) ? A : Bb;
    #pragma unroll
    for (int c = 0; c < 2; ++c)
      #pragma unroll
      for (int db = 0; db < 4; ++db)
        #pragma unroll
        for (int g4 = 0; g4 < 4; ++g4)
          *(float4*)(D + (32 * c + ql) * 132 + 32 * db + 8 * g4 + 4 * hi) =
              make_float4(o[c * 4 + db][4 * g4], o[c * 4 + db][4 * g4 + 1],
                          o[c * 4 + db][4 * g4 + 2], o[c * 4 + db][4 * g4 + 3]);
  }
  __syncthreads();
  if (w == 2 || w == 0) {
    float* D = (w == 2) ? A : Bb;
    #pragma unroll
    for (int c = 0; c < 2; ++c)
      #pragma unroll
      for (int db = 0; db < 4; ++db)
        #pragma unroll
        for (int g4 = 0; g4 < 4; ++g4) {
          float* ptr = D + (32 * c + ql) * 132 + 32 * db + 8 * g4 + 4 * hi;
          float4 tv = *(float4*)ptr;
          tv.x += o[c * 4 + db][4 * g4];
          tv.y += o[c * 4 + db][4 * g4 + 1];
          tv.z += o[c * 4 + db][4 * g4 + 2];
          tv.w += o[c * 4 + db][4 * g4 + 3];
          *(float4*)ptr = tv;
        }
  }
  __syncthreads();
  if (w == 0 || w == 2) {
    const int ch = w >> 1;
    float* outb = out + ((size_t)batch * SEQN + q0) * DIM;
    #pragma unroll
    for (int s2 = 0; s2 < 32; ++s2) {
      const int q = 32 * ch + s2;
      const float iv = Lf[q];
      float2 a2 = *(const float2*)(A + q * 132 + 2 * l);
      float2 b2 = *(const float2*)(Bb + q * 132 + 2 * l);
      *(float2*)(outb + (size_t)q * DIM + 2 * l) =
          make_float2((a2.x + b2.x) * iv, (a2.y + b2.y) * iv);
    }
  }
}

extern "C" void kernel_launch(void* const* d_in, const int* in_sizes, int n_in,
                              void* d_out, int out_size, void* d_ws, size_t ws_size,
                              hipStream_t stream) {
  (void)in_sizes; (void)n_in; (void)out_size; (void)ws_size;
  const float* qk = (const float*)d_in[0];
  const float* v  = (const float*)d_in[1];
  float* out = (float*)d_out;
  size_t nelem = (size_t)BATCH * SEQN * DIM;
  ushort* qfb = (ushort*)d_ws;
  ushort* kfb = qfb + nelem;
  ushort* vfb = kfb + nelem;
  prep_qk<<<BATCH * SEQN / 32, 256, 0, stream>>>(qk, qfb, kfb);
  prep_v <<<BATCH * SEQN / 32, 256, 0, stream>>>(v, vfb);
  attn_kernel<<<BATCH * (SEQN / 64), 256, 0, stream>>>(qfb, kfb, vfb, out);
}